// Round 15
// baseline (185.587 us; speedup 1.0000x reference)
//
#include <hip/hip_runtime.h>
#include <math.h>

#define XD 32
#define HD 128

typedef float f32x16 __attribute__((ext_vector_type(16)));
typedef int v2i __attribute__((ext_vector_type(2)));
typedef int i32x8 __attribute__((ext_vector_type(8)));

#if __has_builtin(__builtin_amdgcn_cvt_pk_fp8_f32)
#define HAVE_CVT_FP8 1
#endif

// ---- scalar f32 -> e4m3fn (RNE), used by prep ----
static __device__ __forceinline__ unsigned char f2e4m3(float f){
  if (!(f==f)) return 0x7F;
  unsigned u = __float_as_uint(f);
  unsigned s = (u>>24)&0x80;
  float a = fabsf(f);
  if (a >= 464.f) return (unsigned char)(s|0x7E);
  if (a < 0.0009765625f) return (unsigned char)s;
  int e = (int)((u>>23)&0xFF) - 127;
  if (e < -6){
    int m = (int)rintf(ldexpf(a, 9));
    if (m >= 8) return (unsigned char)(s|0x08);
    return (unsigned char)(s|(unsigned)m);
  }
  int m = (int)rintf(ldexpf(a, 3-e));
  if (m == 16){ ++e; m = 8; }
  if (e > 8) return (unsigned char)(s|0x7E);
  return (unsigned char)(s | (unsigned)((e+7)<<3) | (unsigned)(m-8));
}

template<bool HI>
static __device__ __forceinline__ int cvtpk_fp8(float a, float b, int old){
#ifdef HAVE_CVT_FP8
  return __builtin_amdgcn_cvt_pk_fp8_f32(a, b, old, HI);
#else
  int w = (int)f2e4m3(a) | ((int)f2e4m3(b) << 8);
  return HI ? ((old & 0x0000FFFF) | (w << 16)) : ((old & (int)0xFFFF0000) | w);
#endif
}

static __device__ __forceinline__ void plswap(int &x, int &y){
#if __has_builtin(__builtin_amdgcn_permlane32_swap)
  v2i r = __builtin_amdgcn_permlane32_swap(x, y, false, false);
  x = r[0]; y = r[1];
#else
  unsigned lane = threadIdx.x & 63u;
  int sx = __shfl_xor(x, 32, 64);
  int sy = __shfl_xor(y, 32, 64);
  int nx = (lane < 32) ? x : sy;
  int ny = (lane < 32) ? sx : y;
  x = nx; y = ny;
#endif
}

// Build one MX K=64 B-frag from two 32x32 f32 C tiles (relu applied).
static __device__ __forceinline__ i32x8 c2mx(const f32x16 &ca, const f32x16 &cb){
  i32x8 fr;
#pragma unroll
  for (int q = 0; q < 4; ++q){
    int x = cvtpk_fp8<false>(fmaxf(ca[q*4+0],0.f), fmaxf(ca[q*4+1],0.f), 0);
    x     = cvtpk_fp8<true >(fmaxf(ca[q*4+2],0.f), fmaxf(ca[q*4+3],0.f), x);
    int y = cvtpk_fp8<false>(fmaxf(cb[q*4+0],0.f), fmaxf(cb[q*4+1],0.f), 0);
    y     = cvtpk_fp8<true >(fmaxf(cb[q*4+2],0.f), fmaxf(cb[q*4+3],0.f), y);
    plswap(x, y);
    fr[q*2]   = x;
    fr[q*2+1] = y;
  }
  return fr;
}

static __device__ __forceinline__ f32x16 mfma_mx(i32x8 a, i32x8 b, f32x16 c){
  return __builtin_amdgcn_mfma_scale_f32_32x32x64_f8f6f4(
           a, b, c, 0, 0, 0, 0x7F7F7F7F, 0, 0x7F7F7F7F);
}

static __device__ __forceinline__ void ld8(const float* __restrict__ p, float* dst){
  float4 a = *(const float4*)p, b = *(const float4*)(p+4);
  dst[0]=a.x; dst[1]=a.y; dst[2]=a.z; dst[3]=a.w;
  dst[4]=b.x; dst[5]=b.y; dst[6]=b.z; dst[7]=b.w;
}

// ---- prep ----
// wip: K=16 A-frags, 12/step (kt=0,1: 8*Wi w/ z col at dead diag; kt=2: 8*bi at k0)
//      frag idx b = i*12 + kt*4 + fo at [(b*64+l)*8]
// w1p/w2p: MX K=64 A-frags (8*W), split-half int4: frag f=fo*2+f2 at [((f*2+h)*64+l)*16]
// wfp: MX A-frags of 64*wf, row0 only, contiguous: frag f=i*2+f2 at [(f*64+l)*32]
// bbp: K=16 bias A-frags: f=0..3 -> 64*b1 at k0, f=4..7 -> 512*b2 at k0
// Mt=M^T
__global__ void prep(const float* __restrict__ Wi, const float* __restrict__ bi,
                     const float* __restrict__ W1, const float* __restrict__ b1,
                     const float* __restrict__ W2, const float* __restrict__ b2,
                     const float* __restrict__ M,  const float* __restrict__ wf,
                     unsigned char* __restrict__ wip, unsigned char* __restrict__ w1p,
                     unsigned char* __restrict__ w2p, unsigned char* __restrict__ wfp,
                     unsigned char* __restrict__ bbp, float* __restrict__ Mt){
  int b = (int)blockIdx.x;
  int l = (int)threadIdx.x;
  int h = l >> 5, cl = l & 31;
  if (b < 384){                       // wip with bias slice
    int i = b / 12, r = b % 12, kt = r >> 2, fo = r & 3;
    int row = fo*32 + cl;
    unsigned char bytes[8];
#pragma unroll
    for (int j = 0; j < 8; ++j){
      float v;
      if (kt < 2){
        int k = kt*16 + h*8 + j;
        int src = (k == i) ? XD : k;
        v = 8.f * Wi[((size_t)i*HD + row)*(XD+1) + src];
      } else {
        v = (h==0 && j==0) ? 8.f * bi[(size_t)i*HD + row] : 0.f;
      }
      bytes[j] = f2e4m3(v);
    }
    long v8; __builtin_memcpy(&v8, bytes, 8);
    *(long*)(wip + ((size_t)b*64 + l)*8) = v8;
  } else if (b < 400){                // W1/W2 MX A-frags, split-half order
    const float* W = (b < 392) ? W1 : W2;
    unsigned char* dp = (b < 392) ? w1p : w2p;
    int f = (b - 384) & 7;
    int fo = f >> 1, f2 = f & 1;
    int row = fo*32 + cl;
    union { unsigned char bt[32]; int4 v[2]; } u;
#pragma unroll
    for (int j = 0; j < 32; ++j)
      u.bt[j] = f2e4m3(8.f * W[(size_t)row*HD + f2*64 + h*32 + j]);
    *(int4*)(dp + ((size_t)((f*2+0)*64 + l))*16) = u.v[0];
    *(int4*)(dp + ((size_t)((f*2+1)*64 + l))*16) = u.v[1];
  } else if (b < 464){                // wf MX A-frags (row 0 only), contiguous
    int f = b - 400;                  // i*2 + f2
    int i = f >> 1, f2 = f & 1;
    union { unsigned char bt[32]; int4 v[2]; } u;
#pragma unroll
    for (int j = 0; j < 32; ++j){
      float v = (cl == 0) ? 64.f * wf[(size_t)i*HD + f2*64 + h*32 + j] : 0.f;
      u.bt[j] = f2e4m3(v);
    }
    *(int4*)(wfp + ((size_t)f*64 + l)*32)      = u.v[0];
    *(int4*)(wfp + ((size_t)f*64 + l)*32 + 16) = u.v[1];
  } else if (b == 464){               // M transpose
#pragma unroll
    for (int t = 0; t < 16; ++t){
      int idx = t*64 + l;
      int i = idx >> 5, k = idx & 31;
      Mt[i*32 + k] = M[k*32 + i];
    }
  } else {                            // bias K=16 A-frags (b1 x4, b2 x4)
#pragma unroll
    for (int f = 0; f < 8; ++f){
      int fo = f & 3;
      int row = fo*32 + cl;
      float v = (f < 4) ? 64.f * b1[row] : 512.f * b2[row];
      unsigned char bytes[8];
#pragma unroll
      for (int j = 0; j < 8; ++j)
        bytes[j] = (h==0 && j==0) ? f2e4m3(v) : 0;
      long v8; __builtin_memcpy(&v8, bytes, 8);
      *(long*)(bbp + ((size_t)f*64 + l)*8) = v8;
    }
  }
}

// pack x_masked B-frags (K=16 fp8 layout) from state, z spliced at k==i
static __device__ __forceinline__ void pack_xb(const float (&st)[16], const float (&mtv)[16],
                                               float zvv, int i, bool hm, long (&xb)[2]){
  int xbi[2][2];
#pragma unroll
  for (int kt = 0; kt < 2; ++kt)
#pragma unroll
    for (int d = 0; d < 2; ++d){
      float v0 = st[kt*8+4*d+0]*mtv[kt*8+4*d+0];
      float v1 = st[kt*8+4*d+1]*mtv[kt*8+4*d+1];
      float v2 = st[kt*8+4*d+2]*mtv[kt*8+4*d+2];
      float v3 = st[kt*8+4*d+3]*mtv[kt*8+4*d+3];
      int w = cvtpk_fp8<false>(v0, v1, 0);
      xbi[kt][d] = cvtpk_fp8<true>(v2, v3, w);
    }
  const int kti = i>>4, di = (i>>2)&1, sh = 8*(i&3);
  const int msk = ~(0xFF << sh);
  int pz = cvtpk_fp8<false>(zvv, 0.f, 0) & 0xFF;
  int ins = pz << sh;
#pragma unroll
  for (int kt = 0; kt < 2; ++kt)
#pragma unroll
    for (int d = 0; d < 2; ++d)
      if (kt == kti && d == di){
        int mod = (xbi[kt][d] & msk) | ins;
        xbi[kt][d] = hm ? mod : xbi[kt][d];
      }
#pragma unroll
  for (int kt = 0; kt < 2; ++kt)
    xb[kt] = (long)(((unsigned long)(unsigned)xbi[kt][0]) |
                    ((unsigned long)(unsigned)xbi[kt][1] << 32));
}

static __device__ __forceinline__ i32x8 ld_mx(const unsigned char* __restrict__ p){
  union { int4 h[2]; i32x8 v; } u;
  u.h[0] = *(const int4*)(p);
  u.h[1] = *(const int4*)(p + 16);
  return u.v;
}

static __device__ __forceinline__ i32x8 ld_mx_lds(const int4* base, int f, int lane){
  union { int4 h[2]; i32x8 v; } u;
  u.h[0] = base[(f*2+0)*64 + lane];
  u.h[1] = base[(f*2+1)*64 + lane];
  return u.v;
}

// ---- main kernel: 512 blocks x 256 threads = 2048 waves = 2 waves/SIMD ----
// r13 structure, but per-step Wi K16-frags stream global->VGPR (24 regs,
// single-buffered, prefetched a full step ahead) -> NO in-loop barrier at all.
// W1/W2 + bias frags in LDS (read-only after one init barrier).
__global__ __launch_bounds__(256) __attribute__((amdgpu_waves_per_eu(2, 2)))
void genkern(const float* __restrict__ x, const float* __restrict__ z,
             const float* __restrict__ bf,
             const unsigned char* __restrict__ wip, const unsigned char* __restrict__ w1p,
             const unsigned char* __restrict__ w2p, const unsigned char* __restrict__ wfp,
             const unsigned char* __restrict__ bbp, const float* __restrict__ Mt,
             float* __restrict__ out)
{
  __shared__ int4 wlds[2048];          // 32 KB: W1 frags 0-7, W2 frags 8-15 (MX)
  __shared__ long wbias[512];          // 4 KB: K=16 bias frags (b1 x4, b2 x4)

  const int tid  = (int)threadIdx.x;
  const int lane = tid & 63;
  const int wv   = tid >> 6;
  const int half = lane >> 5, col = lane & 31;
  const long rbase = (long)blockIdx.x * 128 + wv * 32;

  // weights + bias frags to LDS (once)
  {
    const int4* s1 = (const int4*)w1p;
    const int4* s2 = (const int4*)w2p;
#pragma unroll
    for (int t = 0; t < 4; ++t)
      wlds[t*256 + tid] = s1[t*256 + tid];
#pragma unroll
    for (int t = 0; t < 4; ++t)
      wlds[1024 + t*256 + tid] = s2[t*256 + tid];
#pragma unroll
    for (int t = 0; t < 2; ++t)
      wbias[t*256 + tid] = ((const long*)bbp)[t*256 + tid];
  }

  // out-state: lane(half h) holds k = kt*16 + h*8 + j at slot kt*8+j
  float st[16];
#pragma unroll
  for (int kt = 0; kt < 2; ++kt)
    ld8(x + (rbase + col)*XD + kt*16 + half*8, &st[kt*8]);

  __syncthreads();   // LDS init visible; the ONLY barrier

  f32x16 zro;
#pragma unroll
  for (int q = 0; q < 16; ++q) zro[q] = 0.f;

  const long bconst = (half == 0) ? 0x38L : 0L;   // e4m3 1.0 at k_local=0

  // single-buffered per-step operand registers (prefetched a full step ahead)
  long wif[3][4];                      // 24 arch regs: input-layer K16 frags
  i32x8 wfx[2];                        // epilogue wf MX frags
#pragma unroll
  for (int kt = 0; kt < 3; ++kt)
#pragma unroll
    for (int fo = 0; fo < 4; ++fo)
      wif[kt][fo] = *(const long*)(wip + (((size_t)(kt*4 + fo))*64 + lane)*8);
  wfx[0] = ld_mx(wfp + ((size_t)0*64 + lane)*32);
  wfx[1] = ld_mx(wfp + ((size_t)1*64 + lane)*32);
  float zA = z[(rbase + col)*XD + 0];

#pragma unroll 1
  for (int i = 0; i < XD; ++i){
    const int ip = (i + 1) & (XD - 1);
    const bool hm = (half == ((i>>3)&1));
    const int slot_i = ((i>>4)<<3) | (i&7);
    const float bfv = bf[i];

    float mtv[16];
#pragma unroll
    for (int kt = 0; kt < 2; ++kt)
      ld8(Mt + i*32 + kt*16 + half*8, &mtv[kt*8]);

    long xb[2];
    pack_xb(st, mtv, zA, i, hm, xb);
    zA = z[(rbase + col)*XD + ip];

    // ---- input layer: K=48 via 3x K=16 fp8 MFMA (kt=2 is bias slice), C=zro ----
    f32x16 acc[4];
#pragma unroll
    for (int fo = 0; fo < 4; ++fo)
      acc[fo] = __builtin_amdgcn_mfma_f32_32x32x16_fp8_fp8(wif[0][fo], xb[0], zro, 0,0,0);
#pragma unroll
    for (int fo = 0; fo < 4; ++fo)
      acc[fo] = __builtin_amdgcn_mfma_f32_32x32x16_fp8_fp8(wif[1][fo], xb[1], acc[fo], 0,0,0);
#pragma unroll
    for (int fo = 0; fo < 4; ++fo)
      acc[fo] = __builtin_amdgcn_mfma_f32_32x32x16_fp8_fp8(wif[2][fo], bconst, acc[fo], 0,0,0);
    // prefetch next step's Wi frags (L2-hot; a full step to land)
#pragma unroll
    for (int kt = 0; kt < 3; ++kt)
#pragma unroll
      for (int fo = 0; fo < 4; ++fo)
        wif[kt][fo] = *(const long*)(wip + (((size_t)(ip*12 + kt*4 + fo))*64 + lane)*8);

    // ---- layer 1: bias K-slice MFMA + 2 MX per fo (operands from LDS) ----
    {
      i32x8 mx0 = c2mx(acc[0], acc[1]);
      i32x8 mx1 = c2mx(acc[2], acc[3]);
#pragma unroll
      for (int fo = 0; fo < 4; ++fo){
        long bfr = wbias[fo*64 + lane];
        acc[fo] = __builtin_amdgcn_mfma_f32_32x32x16_fp8_fp8(bfr, bconst, zro, 0,0,0);
      }
#pragma unroll
      for (int fo = 0; fo < 4; ++fo){
        i32x8 w = ld_mx_lds(wlds, fo*2+0, lane);
        acc[fo] = mfma_mx(w, mx0, acc[fo]);
      }
#pragma unroll
      for (int fo = 0; fo < 4; ++fo){
        i32x8 w = ld_mx_lds(wlds, fo*2+1, lane);
        acc[fo] = mfma_mx(w, mx1, acc[fo]);
      }
    }

    // ---- layer 2: bias K-slice MFMA + 2 MX per fo ----
    {
      i32x8 mx0 = c2mx(acc[0], acc[1]);
      i32x8 mx1 = c2mx(acc[2], acc[3]);
#pragma unroll
      for (int fo = 0; fo < 4; ++fo){
        long bfr = wbias[(4+fo)*64 + lane];
        acc[fo] = __builtin_amdgcn_mfma_f32_32x32x16_fp8_fp8(bfr, bconst, zro, 0,0,0);
      }
#pragma unroll
      for (int fo = 0; fo < 4; ++fo){
        i32x8 w = ld_mx_lds(wlds, 8 + fo*2+0, lane);
        acc[fo] = mfma_mx(w, mx0, acc[fo]);
      }
#pragma unroll
      for (int fo = 0; fo < 4; ++fo){
        i32x8 w = ld_mx_lds(wlds, 8 + fo*2+1, lane);
        acc[fo] = mfma_mx(w, mx1, acc[fo]);
      }
    }

    // ---- epilogue: u = (64wf).fp8(relu(512 h3)) via 2-chain MX, C=zro ----
    {
      i32x8 mx0 = c2mx(acc[0], acc[1]);
      i32x8 mx1 = c2mx(acc[2], acc[3]);
      f32x16 e = mfma_mx(wfx[0], mx0, zro);
      e = mfma_mx(wfx[1], mx1, e);
      float u = e[0];
      float s = __shfl_xor(u, 32, 64);
      float t = half ? s : u;
      float v = 1.f/(1.f + __expf(-(t*(1.f/32768.f) + bfv)));
#pragma unroll
      for (int q = 0; q < 16; ++q)
        if (q == slot_i)
          st[q] = hm ? v : st[q];
    }
    // prefetch next step's wf frags (global, L2-hot)
    wfx[0] = ld_mx(wfp + ((size_t)(ip*2 + 0)*64 + lane)*32);
    wfx[1] = ld_mx(wfp + ((size_t)(ip*2 + 1)*64 + lane)*32);
  }

  // write out
#pragma unroll
  for (int kt = 0; kt < 2; ++kt){
    float* p = out + (rbase + col)*XD + kt*16 + half*8;
    float4 a, b;
    a.x = st[kt*8+0]; a.y = st[kt*8+1]; a.z = st[kt*8+2]; a.w = st[kt*8+3];
    b.x = st[kt*8+4]; b.y = st[kt*8+5]; b.z = st[kt*8+6]; b.w = st[kt*8+7];
    *(float4*)p = a;
    *(float4*)(p+4) = b;
  }
}

extern "C" void kernel_launch(void* const* d_in, const int* in_sizes, int n_in,
                              void* d_out, int out_size, void* d_ws, size_t ws_size,
                              hipStream_t stream){
  (void)in_sizes; (void)n_in; (void)out_size; (void)ws_size;
  const float* x  = (const float*)d_in[0];
  const float* z  = (const float*)d_in[1];
  const float* M  = (const float*)d_in[2];
  const float* Wi = (const float*)d_in[3];
  const float* bi = (const float*)d_in[4];
  const float* wf = (const float*)d_in[5];
  const float* bf = (const float*)d_in[6];
  const float* W1 = (const float*)d_in[7];
  const float* b1 = (const float*)d_in[8];
  const float* W2 = (const float*)d_in[9];
  const float* b2 = (const float*)d_in[10];

  unsigned char* wip = (unsigned char*)d_ws;            // 384*512 = 196608
  unsigned char* w1p = wip + 196608;                    // 16384
  unsigned char* w2p = w1p + 16384;                     // 16384
  unsigned char* wfp = w2p + 16384;                     // 131072
  unsigned char* bbp = wfp + 131072;                    // 4096
  float*         Mt  = (float*)(bbp + 4096);            // 4096

  prep<<<dim3(466), dim3(64), 0, stream>>>(Wi, bi, W1, b1, W2, b2, M, wf,
                                           wip, w1p, w2p, wfp, bbp, Mt);
  genkern<<<dim3(512), dim3(256), 0, stream>>>(x, z, bf, wip, w1p, w2p, wfp, bbp,
                                               Mt, (float*)d_out);
}

// Round 16
// 173.495 us; speedup vs baseline: 1.0697x; 1.0697x over previous
//
#include <hip/hip_runtime.h>
#include <math.h>

#define XD 32
#define HD 128

typedef float f32x16 __attribute__((ext_vector_type(16)));
typedef int v2i __attribute__((ext_vector_type(2)));
typedef int i32x8 __attribute__((ext_vector_type(8)));

#if __has_builtin(__builtin_amdgcn_cvt_pk_fp8_f32)
#define HAVE_CVT_FP8 1
#endif

// ---- scalar f32 -> e4m3fn (RNE), used by prep ----
static __device__ __forceinline__ unsigned char f2e4m3(float f){
  if (!(f==f)) return 0x7F;
  unsigned u = __float_as_uint(f);
  unsigned s = (u>>24)&0x80;
  float a = fabsf(f);
  if (a >= 464.f) return (unsigned char)(s|0x7E);
  if (a < 0.0009765625f) return (unsigned char)s;
  int e = (int)((u>>23)&0xFF) - 127;
  if (e < -6){
    int m = (int)rintf(ldexpf(a, 9));
    if (m >= 8) return (unsigned char)(s|0x08);
    return (unsigned char)(s|(unsigned)m);
  }
  int m = (int)rintf(ldexpf(a, 3-e));
  if (m == 16){ ++e; m = 8; }
  if (e > 8) return (unsigned char)(s|0x7E);
  return (unsigned char)(s | (unsigned)((e+7)<<3) | (unsigned)(m-8));
}

template<bool HI>
static __device__ __forceinline__ int cvtpk_fp8(float a, float b, int old){
#ifdef HAVE_CVT_FP8
  return __builtin_amdgcn_cvt_pk_fp8_f32(a, b, old, HI);
#else
  int w = (int)f2e4m3(a) | ((int)f2e4m3(b) << 8);
  return HI ? ((old & 0x0000FFFF) | (w << 16)) : ((old & (int)0xFFFF0000) | w);
#endif
}

static __device__ __forceinline__ void plswap(int &x, int &y){
#if __has_builtin(__builtin_amdgcn_permlane32_swap)
  v2i r = __builtin_amdgcn_permlane32_swap(x, y, false, false);
  x = r[0]; y = r[1];
#else
  unsigned lane = threadIdx.x & 63u;
  int sx = __shfl_xor(x, 32, 64);
  int sy = __shfl_xor(y, 32, 64);
  int nx = (lane < 32) ? x : sy;
  int ny = (lane < 32) ? sx : y;
  x = nx; y = ny;
#endif
}

// Build one MX K=64 B-frag from two 32x32 f32 C tiles (relu applied).
static __device__ __forceinline__ i32x8 c2mx(const f32x16 &ca, const f32x16 &cb){
  i32x8 fr;
#pragma unroll
  for (int q = 0; q < 4; ++q){
    int x = cvtpk_fp8<false>(fmaxf(ca[q*4+0],0.f), fmaxf(ca[q*4+1],0.f), 0);
    x     = cvtpk_fp8<true >(fmaxf(ca[q*4+2],0.f), fmaxf(ca[q*4+3],0.f), x);
    int y = cvtpk_fp8<false>(fmaxf(cb[q*4+0],0.f), fmaxf(cb[q*4+1],0.f), 0);
    y     = cvtpk_fp8<true >(fmaxf(cb[q*4+2],0.f), fmaxf(cb[q*4+3],0.f), y);
    plswap(x, y);
    fr[q*2]   = x;
    fr[q*2+1] = y;
  }
  return fr;
}

static __device__ __forceinline__ f32x16 mfma_mx(i32x8 a, i32x8 b, f32x16 c){
  return __builtin_amdgcn_mfma_scale_f32_32x32x64_f8f6f4(
           a, b, c, 0, 0, 0, 0x7F7F7F7F, 0, 0x7F7F7F7F);
}

static __device__ __forceinline__ void ld8(const float* __restrict__ p, float* dst){
  float4 a = *(const float4*)p, b = *(const float4*)(p+4);
  dst[0]=a.x; dst[1]=a.y; dst[2]=a.z; dst[3]=a.w;
  dst[4]=b.x; dst[5]=b.y; dst[6]=b.z; dst[7]=b.w;
}

// ---- prep (identical to r13) ----
__global__ void prep(const float* __restrict__ Wi, const float* __restrict__ bi,
                     const float* __restrict__ W1, const float* __restrict__ b1,
                     const float* __restrict__ W2, const float* __restrict__ b2,
                     const float* __restrict__ M,  const float* __restrict__ wf,
                     unsigned char* __restrict__ wip, unsigned char* __restrict__ w1p,
                     unsigned char* __restrict__ w2p, unsigned char* __restrict__ wfp,
                     unsigned char* __restrict__ bbp, float* __restrict__ Mt){
  int b = (int)blockIdx.x;
  int l = (int)threadIdx.x;
  int h = l >> 5, cl = l & 31;
  if (b < 384){                       // wip with bias slice
    int i = b / 12, r = b % 12, kt = r >> 2, fo = r & 3;
    int row = fo*32 + cl;
    unsigned char bytes[8];
#pragma unroll
    for (int j = 0; j < 8; ++j){
      float v;
      if (kt < 2){
        int k = kt*16 + h*8 + j;
        int src = (k == i) ? XD : k;
        v = 8.f * Wi[((size_t)i*HD + row)*(XD+1) + src];
      } else {
        v = (h==0 && j==0) ? 8.f * bi[(size_t)i*HD + row] : 0.f;
      }
      bytes[j] = f2e4m3(v);
    }
    long v8; __builtin_memcpy(&v8, bytes, 8);
    *(long*)(wip + ((size_t)b*64 + l)*8) = v8;
  } else if (b < 400){                // W1/W2 MX A-frags, split-half order
    const float* W = (b < 392) ? W1 : W2;
    unsigned char* dp = (b < 392) ? w1p : w2p;
    int f = (b - 384) & 7;
    int fo = f >> 1, f2 = f & 1;
    int row = fo*32 + cl;
    union { unsigned char bt[32]; int4 v[2]; } u;
#pragma unroll
    for (int j = 0; j < 32; ++j)
      u.bt[j] = f2e4m3(8.f * W[(size_t)row*HD + f2*64 + h*32 + j]);
    *(int4*)(dp + ((size_t)((f*2+0)*64 + l))*16) = u.v[0];
    *(int4*)(dp + ((size_t)((f*2+1)*64 + l))*16) = u.v[1];
  } else if (b < 464){                // wf MX A-frags (row 0 only), contiguous
    int f = b - 400;                  // i*2 + f2
    int i = f >> 1, f2 = f & 1;
    union { unsigned char bt[32]; int4 v[2]; } u;
#pragma unroll
    for (int j = 0; j < 32; ++j){
      float v = (cl == 0) ? 64.f * wf[(size_t)i*HD + f2*64 + h*32 + j] : 0.f;
      u.bt[j] = f2e4m3(v);
    }
    *(int4*)(wfp + ((size_t)f*64 + l)*32)      = u.v[0];
    *(int4*)(wfp + ((size_t)f*64 + l)*32 + 16) = u.v[1];
  } else if (b == 464){               // M transpose
#pragma unroll
    for (int t = 0; t < 16; ++t){
      int idx = t*64 + l;
      int i = idx >> 5, k = idx & 31;
      Mt[i*32 + k] = M[k*32 + i];
    }
  } else {                            // bias K=16 A-frags (b1 x4, b2 x4)
#pragma unroll
    for (int f = 0; f < 8; ++f){
      int fo = f & 3;
      int row = fo*32 + cl;
      float v = (f < 4) ? 64.f * b1[row] : 512.f * b2[row];
      unsigned char bytes[8];
#pragma unroll
      for (int j = 0; j < 8; ++j)
        bytes[j] = (h==0 && j==0) ? f2e4m3(v) : 0;
      long v8; __builtin_memcpy(&v8, bytes, 8);
      *(long*)(bbp + ((size_t)f*64 + l)*8) = v8;
    }
  }
}

// pack x_masked B-frags (K=16 fp8 layout) from state, z spliced at k==i
static __device__ __forceinline__ void pack_xb(const float (&st)[16], const float (&mtv)[16],
                                               float zvv, int i, bool hm, long (&xb)[2]){
  int xbi[2][2];
#pragma unroll
  for (int kt = 0; kt < 2; ++kt)
#pragma unroll
    for (int d = 0; d < 2; ++d){
      float v0 = st[kt*8+4*d+0]*mtv[kt*8+4*d+0];
      float v1 = st[kt*8+4*d+1]*mtv[kt*8+4*d+1];
      float v2 = st[kt*8+4*d+2]*mtv[kt*8+4*d+2];
      float v3 = st[kt*8+4*d+3]*mtv[kt*8+4*d+3];
      int w = cvtpk_fp8<false>(v0, v1, 0);
      xbi[kt][d] = cvtpk_fp8<true>(v2, v3, w);
    }
  const int kti = i>>4, di = (i>>2)&1, sh = 8*(i&3);
  const int msk = ~(0xFF << sh);
  int pz = cvtpk_fp8<false>(zvv, 0.f, 0) & 0xFF;
  int ins = pz << sh;
#pragma unroll
  for (int kt = 0; kt < 2; ++kt)
#pragma unroll
    for (int d = 0; d < 2; ++d)
      if (kt == kti && d == di){
        int mod = (xbi[kt][d] & msk) | ins;
        xbi[kt][d] = hm ? mod : xbi[kt][d];
      }
#pragma unroll
  for (int kt = 0; kt < 2; ++kt)
    xb[kt] = (long)(((unsigned long)(unsigned)xbi[kt][0]) |
                    ((unsigned long)(unsigned)xbi[kt][1] << 32));
}

static __device__ __forceinline__ i32x8 ld_mx(const unsigned char* __restrict__ p){
  union { int4 h[2]; i32x8 v; } u;
  u.h[0] = *(const int4*)(p);
  u.h[1] = *(const int4*)(p + 16);
  return u.v;
}

static __device__ __forceinline__ i32x8 ld_mx_lds(const int4* base, int f, int lane){
  union { int4 h[2]; i32x8 v; } u;
  u.h[0] = base[(f*2+0)*64 + lane];
  u.h[1] = base[(f*2+1)*64 + lane];
  return u.v;
}

// ---- main kernel: 256 blocks x 256 threads = 1024 waves = 1 wave/SIMD ----
// Two SKEWED 32-row tiles per wave: tile B's VALU phases sit between tile A's
// MFMA clusters (and vice versa), hiding VALU under the matrix pipe within the
// wave. 512-reg budget (1 wave/SIMD) -> no spill. W1/W2+bias in LDS; Wi/wf
// frags register-prefetched one step ahead. NO in-loop barrier.
__global__ void __launch_bounds__(256, 1)
genkern(const float* __restrict__ x, const float* __restrict__ z,
        const float* __restrict__ bf,
        const unsigned char* __restrict__ wip, const unsigned char* __restrict__ w1p,
        const unsigned char* __restrict__ w2p, const unsigned char* __restrict__ wfp,
        const unsigned char* __restrict__ bbp, const float* __restrict__ Mt,
        float* __restrict__ out)
{
  __shared__ int4 wlds[2048];          // 32 KB: W1 frags 0-7, W2 frags 8-15 (MX)
  __shared__ long wbias[512];          // 4 KB: K=16 bias frags (b1 x4, b2 x4)

  const int tid  = (int)threadIdx.x;
  const int lane = tid & 63;
  const int wv   = tid >> 6;
  const int half = lane >> 5, col = lane & 31;
  const long rbase = (long)blockIdx.x * 256 + wv * 64;

  {
    const int4* s1 = (const int4*)w1p;
    const int4* s2 = (const int4*)w2p;
#pragma unroll
    for (int t = 0; t < 4; ++t)
      wlds[t*256 + tid] = s1[t*256 + tid];
#pragma unroll
    for (int t = 0; t < 4; ++t)
      wlds[1024 + t*256 + tid] = s2[t*256 + tid];
#pragma unroll
    for (int t = 0; t < 2; ++t)
      wbias[t*256 + tid] = ((const long*)bbp)[t*256 + tid];
  }

  // out-state per tile: lane(half h) holds k = kt*16 + h*8 + j at slot kt*8+j
  float stA[16], stB[16];
#pragma unroll
  for (int kt = 0; kt < 2; ++kt){
    ld8(x + (rbase + col)*XD + kt*16 + half*8,      &stA[kt*8]);
    ld8(x + (rbase + 32 + col)*XD + kt*16 + half*8, &stB[kt*8]);
  }

  __syncthreads();   // LDS init visible; the ONLY barrier

  f32x16 zro;
#pragma unroll
  for (int q = 0; q < 16; ++q) zro[q] = 0.f;

  const long bconst = (half == 0) ? 0x38L : 0L;   // e4m3 1.0 at k_local=0

  // prefetched per-step operands (shared by both tiles)
  long wif[3][4];                      // input-layer K16 frags (24 regs)
  i32x8 wfx[2];                        // epilogue wf MX frags (16 regs)
#pragma unroll
  for (int kt = 0; kt < 3; ++kt)
#pragma unroll
    for (int fo = 0; fo < 4; ++fo)
      wif[kt][fo] = *(const long*)(wip + (((size_t)(kt*4 + fo))*64 + lane)*8);
  wfx[0] = ld_mx(wfp + ((size_t)0*64 + lane)*32);
  wfx[1] = ld_mx(wfp + ((size_t)1*64 + lane)*32);
  float zA = z[(rbase + col)*XD + 0];
  float zB = z[(rbase + 32 + col)*XD + 0];

#pragma unroll 1
  for (int i = 0; i < XD; ++i){
    const int ip = (i + 1) & (XD - 1);
    const bool hm = (half == ((i>>3)&1));
    const int slot_i = ((i>>4)<<3) | (i&7);
    const float bfv = bf[i];

    float mtv[16];
#pragma unroll
    for (int kt = 0; kt < 2; ++kt)
      ld8(Mt + i*32 + kt*16 + half*8, &mtv[kt*8]);

    long xbA[2], xbB[2];
    pack_xb(stA, mtv, zA, i, hm, xbA);
    pack_xb(stB, mtv, zB, i, hm, xbB);
    zA = z[(rbase + col)*XD + ip];
    zB = z[(rbase + 32 + col)*XD + ip];

    // ---- input layer A then B: K=48 via 3x K=16 fp8 MFMA each, C=zro ----
    f32x16 accA[4], accB[4];
#pragma unroll
    for (int fo = 0; fo < 4; ++fo)
      accA[fo] = __builtin_amdgcn_mfma_f32_32x32x16_fp8_fp8(wif[0][fo], xbA[0], zro, 0,0,0);
#pragma unroll
    for (int fo = 0; fo < 4; ++fo)
      accA[fo] = __builtin_amdgcn_mfma_f32_32x32x16_fp8_fp8(wif[1][fo], xbA[1], accA[fo], 0,0,0);
#pragma unroll
    for (int fo = 0; fo < 4; ++fo)
      accA[fo] = __builtin_amdgcn_mfma_f32_32x32x16_fp8_fp8(wif[2][fo], bconst, accA[fo], 0,0,0);
#pragma unroll
    for (int fo = 0; fo < 4; ++fo)
      accB[fo] = __builtin_amdgcn_mfma_f32_32x32x16_fp8_fp8(wif[0][fo], xbB[0], zro, 0,0,0);
#pragma unroll
    for (int fo = 0; fo < 4; ++fo)
      accB[fo] = __builtin_amdgcn_mfma_f32_32x32x16_fp8_fp8(wif[1][fo], xbB[1], accB[fo], 0,0,0);
#pragma unroll
    for (int fo = 0; fo < 4; ++fo)
      accB[fo] = __builtin_amdgcn_mfma_f32_32x32x16_fp8_fp8(wif[2][fo], bconst, accB[fo], 0,0,0);

    // prefetch next step's Wi frags (L2-hot; full step to land)
#pragma unroll
    for (int kt = 0; kt < 3; ++kt)
#pragma unroll
      for (int fo = 0; fo < 4; ++fo)
        wif[kt][fo] = *(const long*)(wip + (((size_t)(ip*12 + kt*4 + fo))*64 + lane)*8);

    // ---- skewed middle: c2mx(A); L1(A) || c2mx(B); L1(B) || c2mx2(A); ... ----
    {
      i32x8 mxA0 = c2mx(accA[0], accA[1]);
      i32x8 mxA1 = c2mx(accA[2], accA[3]);
      // L1(A)
#pragma unroll
      for (int fo = 0; fo < 4; ++fo){
        long bfr = wbias[fo*64 + lane];
        accA[fo] = __builtin_amdgcn_mfma_f32_32x32x16_fp8_fp8(bfr, bconst, zro, 0,0,0);
      }
#pragma unroll
      for (int fo = 0; fo < 4; ++fo){
        i32x8 w = ld_mx_lds(wlds, fo*2+0, lane);
        accA[fo] = mfma_mx(w, mxA0, accA[fo]);
      }
#pragma unroll
      for (int fo = 0; fo < 4; ++fo){
        i32x8 w = ld_mx_lds(wlds, fo*2+1, lane);
        accA[fo] = mfma_mx(w, mxA1, accA[fo]);
      }
      // c2mx(B) overlaps L1(A) drain; L1(B)
      i32x8 mxB0 = c2mx(accB[0], accB[1]);
      i32x8 mxB1 = c2mx(accB[2], accB[3]);
#pragma unroll
      for (int fo = 0; fo < 4; ++fo){
        long bfr = wbias[fo*64 + lane];
        accB[fo] = __builtin_amdgcn_mfma_f32_32x32x16_fp8_fp8(bfr, bconst, zro, 0,0,0);
      }
#pragma unroll
      for (int fo = 0; fo < 4; ++fo){
        i32x8 w = ld_mx_lds(wlds, fo*2+0, lane);
        accB[fo] = mfma_mx(w, mxB0, accB[fo]);
      }
#pragma unroll
      for (int fo = 0; fo < 4; ++fo){
        i32x8 w = ld_mx_lds(wlds, fo*2+1, lane);
        accB[fo] = mfma_mx(w, mxB1, accB[fo]);
      }
      // c2mx2(A) overlaps L1(B); L2(A)
      i32x8 nA0 = c2mx(accA[0], accA[1]);
      i32x8 nA1 = c2mx(accA[2], accA[3]);
#pragma unroll
      for (int fo = 0; fo < 4; ++fo){
        long bfr = wbias[(4+fo)*64 + lane];
        accA[fo] = __builtin_amdgcn_mfma_f32_32x32x16_fp8_fp8(bfr, bconst, zro, 0,0,0);
      }
#pragma unroll
      for (int fo = 0; fo < 4; ++fo){
        i32x8 w = ld_mx_lds(wlds, 8 + fo*2+0, lane);
        accA[fo] = mfma_mx(w, nA0, accA[fo]);
      }
#pragma unroll
      for (int fo = 0; fo < 4; ++fo){
        i32x8 w = ld_mx_lds(wlds, 8 + fo*2+1, lane);
        accA[fo] = mfma_mx(w, nA1, accA[fo]);
      }
      // c2mx2(B) overlaps L2(A); L2(B)
      i32x8 nB0 = c2mx(accB[0], accB[1]);
      i32x8 nB1 = c2mx(accB[2], accB[3]);
#pragma unroll
      for (int fo = 0; fo < 4; ++fo){
        long bfr = wbias[(4+fo)*64 + lane];
        accB[fo] = __builtin_amdgcn_mfma_f32_32x32x16_fp8_fp8(bfr, bconst, zro, 0,0,0);
      }
#pragma unroll
      for (int fo = 0; fo < 4; ++fo){
        i32x8 w = ld_mx_lds(wlds, 8 + fo*2+0, lane);
        accB[fo] = mfma_mx(w, nB0, accB[fo]);
      }
#pragma unroll
      for (int fo = 0; fo < 4; ++fo){
        i32x8 w = ld_mx_lds(wlds, 8 + fo*2+1, lane);
        accB[fo] = mfma_mx(w, nB1, accB[fo]);
      }
    }

    // ---- epilogues: epi(A) overlaps L2(B) drain; then epi(B) ----
    {
      i32x8 eA0 = c2mx(accA[0], accA[1]);
      i32x8 eA1 = c2mx(accA[2], accA[3]);
      f32x16 eA = mfma_mx(wfx[0], eA0, zro);
      eA = mfma_mx(wfx[1], eA1, eA);
      i32x8 eB0 = c2mx(accB[0], accB[1]);
      i32x8 eB1 = c2mx(accB[2], accB[3]);
      f32x16 eB = mfma_mx(wfx[0], eB0, zro);
      eB = mfma_mx(wfx[1], eB1, eB);
      float uA = eA[0], uB = eB[0];
      float sA = __shfl_xor(uA, 32, 64);
      float sB = __shfl_xor(uB, 32, 64);
      float tA = half ? sA : uA;
      float tB = half ? sB : uB;
      float vA = 1.f/(1.f + __expf(-(tA*(1.f/32768.f) + bfv)));
      float vB = 1.f/(1.f + __expf(-(tB*(1.f/32768.f) + bfv)));
#pragma unroll
      for (int q = 0; q < 16; ++q)
        if (q == slot_i){
          stA[q] = hm ? vA : stA[q];
          stB[q] = hm ? vB : stB[q];
        }
    }
    // prefetch next step's wf frags (global, L2-hot)
    wfx[0] = ld_mx(wfp + ((size_t)(ip*2 + 0)*64 + lane)*32);
    wfx[1] = ld_mx(wfp + ((size_t)(ip*2 + 1)*64 + lane)*32);
  }

  // write out both tiles
#pragma unroll
  for (int kt = 0; kt < 2; ++kt){
    float* pA = out + (rbase + col)*XD + kt*16 + half*8;
    float* pB = out + (rbase + 32 + col)*XD + kt*16 + half*8;
    float4 a, b;
    a.x = stA[kt*8+0]; a.y = stA[kt*8+1]; a.z = stA[kt*8+2]; a.w = stA[kt*8+3];
    b.x = stA[kt*8+4]; b.y = stA[kt*8+5]; b.z = stA[kt*8+6]; b.w = stA[kt*8+7];
    *(float4*)pA = a; *(float4*)(pA+4) = b;
    a.x = stB[kt*8+0]; a.y = stB[kt*8+1]; a.z = stB[kt*8+2]; a.w = stB[kt*8+3];
    b.x = stB[kt*8+4]; b.y = stB[kt*8+5]; b.z = stB[kt*8+6]; b.w = stB[kt*8+7];
    *(float4*)pB = a; *(float4*)(pB+4) = b;
  }
}

extern "C" void kernel_launch(void* const* d_in, const int* in_sizes, int n_in,
                              void* d_out, int out_size, void* d_ws, size_t ws_size,
                              hipStream_t stream){
  (void)in_sizes; (void)n_in; (void)out_size; (void)ws_size;
  const float* x  = (const float*)d_in[0];
  const float* z  = (const float*)d_in[1];
  const float* M  = (const float*)d_in[2];
  const float* Wi = (const float*)d_in[3];
  const float* bi = (const float*)d_in[4];
  const float* wf = (const float*)d_in[5];
  const float* bf = (const float*)d_in[6];
  const float* W1 = (const float*)d_in[7];
  const float* b1 = (const float*)d_in[8];
  const float* W2 = (const float*)d_in[9];
  const float* b2 = (const float*)d_in[10];

  unsigned char* wip = (unsigned char*)d_ws;            // 384*512 = 196608
  unsigned char* w1p = wip + 196608;                    // 16384
  unsigned char* w2p = w1p + 16384;                     // 16384
  unsigned char* wfp = w2p + 16384;                     // 131072
  unsigned char* bbp = wfp + 131072;                    // 4096
  float*         Mt  = (float*)(bbp + 4096);            // 4096

  prep<<<dim3(466), dim3(64), 0, stream>>>(Wi, bi, W1, b1, W2, b2, M, wf,
                                           wip, w1p, w2p, wfp, bbp, Mt);
  genkern<<<dim3(256), dim3(256), 0, stream>>>(x, z, bf, wip, w1p, w2p, wfp, bbp,
                                               Mt, (float*)d_out);
}

// Round 17
// 143.679 us; speedup vs baseline: 1.2917x; 1.2075x over previous
//
#include <hip/hip_runtime.h>
#include <math.h>

#define XD 32
#define HD 128

typedef float f32x16 __attribute__((ext_vector_type(16)));
typedef int v2i __attribute__((ext_vector_type(2)));
typedef int i32x8 __attribute__((ext_vector_type(8)));

#if __has_builtin(__builtin_amdgcn_cvt_pk_fp8_f32)
#define HAVE_CVT_FP8 1
#endif

// ---- scalar f32 -> e4m3fn (RNE), used by prep ----
static __device__ __forceinline__ unsigned char f2e4m3(float f){
  if (!(f==f)) return 0x7F;
  unsigned u = __float_as_uint(f);
  unsigned s = (u>>24)&0x80;
  float a = fabsf(f);
  if (a >= 464.f) return (unsigned char)(s|0x7E);
  if (a < 0.0009765625f) return (unsigned char)s;
  int e = (int)((u>>23)&0xFF) - 127;
  if (e < -6){
    int m = (int)rintf(ldexpf(a, 9));
    if (m >= 8) return (unsigned char)(s|0x08);
    return (unsigned char)(s|(unsigned)m);
  }
  int m = (int)rintf(ldexpf(a, 3-e));
  if (m == 16){ ++e; m = 8; }
  if (e > 8) return (unsigned char)(s|0x7E);
  return (unsigned char)(s | (unsigned)((e+7)<<3) | (unsigned)(m-8));
}

template<bool HI>
static __device__ __forceinline__ int cvtpk_fp8(float a, float b, int old){
#ifdef HAVE_CVT_FP8
  return __builtin_amdgcn_cvt_pk_fp8_f32(a, b, old, HI);
#else
  int w = (int)f2e4m3(a) | ((int)f2e4m3(b) << 8);
  return HI ? ((old & 0x0000FFFF) | (w << 16)) : ((old & (int)0xFFFF0000) | w);
#endif
}

static __device__ __forceinline__ void plswap(int &x, int &y){
#if __has_builtin(__builtin_amdgcn_permlane32_swap)
  v2i r = __builtin_amdgcn_permlane32_swap(x, y, false, false);
  x = r[0]; y = r[1];
#else
  unsigned lane = threadIdx.x & 63u;
  int sx = __shfl_xor(x, 32, 64);
  int sy = __shfl_xor(y, 32, 64);
  int nx = (lane < 32) ? x : sy;
  int ny = (lane < 32) ? sx : y;
  x = nx; y = ny;
#endif
}

// Build one MX K=64 B-frag from two 32x32 f32 C tiles (relu applied).
static __device__ __forceinline__ i32x8 c2mx(const f32x16 &ca, const f32x16 &cb){
  i32x8 fr;
#pragma unroll
  for (int q = 0; q < 4; ++q){
    int x = cvtpk_fp8<false>(fmaxf(ca[q*4+0],0.f), fmaxf(ca[q*4+1],0.f), 0);
    x     = cvtpk_fp8<true >(fmaxf(ca[q*4+2],0.f), fmaxf(ca[q*4+3],0.f), x);
    int y = cvtpk_fp8<false>(fmaxf(cb[q*4+0],0.f), fmaxf(cb[q*4+1],0.f), 0);
    y     = cvtpk_fp8<true >(fmaxf(cb[q*4+2],0.f), fmaxf(cb[q*4+3],0.f), y);
    plswap(x, y);
    fr[q*2]   = x;
    fr[q*2+1] = y;
  }
  return fr;
}

static __device__ __forceinline__ f32x16 mfma_mx(i32x8 a, i32x8 b, f32x16 c){
  return __builtin_amdgcn_mfma_scale_f32_32x32x64_f8f6f4(
           a, b, c, 0, 0, 0, 0x7F7F7F7F, 0, 0x7F7F7F7F);
}

static __device__ __forceinline__ void ld8(const float* __restrict__ p, float* dst){
  float4 a = *(const float4*)p, b = *(const float4*)(p+4);
  dst[0]=a.x; dst[1]=a.y; dst[2]=a.z; dst[3]=a.w;
  dst[4]=b.x; dst[5]=b.y; dst[6]=b.z; dst[7]=b.w;
}

// ---- prep ----
// wip: K=16 A-frags, 12/step (kt=0,1: 8*Wi w/ z col at dead diag; kt=2: 8*bi at k0)
//      frag idx b = i*12 + kt*4 + fo at [(b*64+l)*8]
// w1p/w2p: MX K=64 A-frags (8*W), split-half int4: frag f=fo*2+f2 at [((f*2+h)*64+l)*16]
// wfp: MX A-frags of 64*wf, row0 only, contiguous: frag f=i*2+f2 at [(f*64+l)*32]
// bbp: K=16 bias A-frags: f=0..3 -> 64*b1 at k0, f=4..7 -> 512*b2 at k0
// Mt=M^T
__global__ void prep(const float* __restrict__ Wi, const float* __restrict__ bi,
                     const float* __restrict__ W1, const float* __restrict__ b1,
                     const float* __restrict__ W2, const float* __restrict__ b2,
                     const float* __restrict__ M,  const float* __restrict__ wf,
                     unsigned char* __restrict__ wip, unsigned char* __restrict__ w1p,
                     unsigned char* __restrict__ w2p, unsigned char* __restrict__ wfp,
                     unsigned char* __restrict__ bbp, float* __restrict__ Mt){
  int b = (int)blockIdx.x;
  int l = (int)threadIdx.x;
  int h = l >> 5, cl = l & 31;
  if (b < 384){                       // wip with bias slice
    int i = b / 12, r = b % 12, kt = r >> 2, fo = r & 3;
    int row = fo*32 + cl;
    unsigned char bytes[8];
#pragma unroll
    for (int j = 0; j < 8; ++j){
      float v;
      if (kt < 2){
        int k = kt*16 + h*8 + j;
        int src = (k == i) ? XD : k;
        v = 8.f * Wi[((size_t)i*HD + row)*(XD+1) + src];
      } else {
        v = (h==0 && j==0) ? 8.f * bi[(size_t)i*HD + row] : 0.f;
      }
      bytes[j] = f2e4m3(v);
    }
    long v8; __builtin_memcpy(&v8, bytes, 8);
    *(long*)(wip + ((size_t)b*64 + l)*8) = v8;
  } else if (b < 400){                // W1/W2 MX A-frags, split-half order
    const float* W = (b < 392) ? W1 : W2;
    unsigned char* dp = (b < 392) ? w1p : w2p;
    int f = (b - 384) & 7;
    int fo = f >> 1, f2 = f & 1;
    int row = fo*32 + cl;
    union { unsigned char bt[32]; int4 v[2]; } u;
#pragma unroll
    for (int j = 0; j < 32; ++j)
      u.bt[j] = f2e4m3(8.f * W[(size_t)row*HD + f2*64 + h*32 + j]);
    *(int4*)(dp + ((size_t)((f*2+0)*64 + l))*16) = u.v[0];
    *(int4*)(dp + ((size_t)((f*2+1)*64 + l))*16) = u.v[1];
  } else if (b < 464){                // wf MX A-frags (row 0 only), contiguous
    int f = b - 400;                  // i*2 + f2
    int i = f >> 1, f2 = f & 1;
    union { unsigned char bt[32]; int4 v[2]; } u;
#pragma unroll
    for (int j = 0; j < 32; ++j){
      float v = (cl == 0) ? 64.f * wf[(size_t)i*HD + f2*64 + h*32 + j] : 0.f;
      u.bt[j] = f2e4m3(v);
    }
    *(int4*)(wfp + ((size_t)f*64 + l)*32)      = u.v[0];
    *(int4*)(wfp + ((size_t)f*64 + l)*32 + 16) = u.v[1];
  } else if (b == 464){               // M transpose
#pragma unroll
    for (int t = 0; t < 16; ++t){
      int idx = t*64 + l;
      int i = idx >> 5, k = idx & 31;
      Mt[i*32 + k] = M[k*32 + i];
    }
  } else {                            // bias K=16 A-frags (b1 x4, b2 x4)
#pragma unroll
    for (int f = 0; f < 8; ++f){
      int fo = f & 3;
      int row = fo*32 + cl;
      float v = (f < 4) ? 64.f * b1[row] : 512.f * b2[row];
      unsigned char bytes[8];
#pragma unroll
      for (int j = 0; j < 8; ++j)
        bytes[j] = (h==0 && j==0) ? f2e4m3(v) : 0;
      long v8; __builtin_memcpy(&v8, bytes, 8);
      *(long*)(bbp + ((size_t)f*64 + l)*8) = v8;
    }
  }
}

// pack x_masked B-frags (K=16 fp8 layout) from state, z spliced at k==i
static __device__ __forceinline__ void pack_xb(const float (&st)[16], const float (&mtv)[16],
                                               float zvv, int i, bool hm, long (&xb)[2]){
  int xbi[2][2];
#pragma unroll
  for (int kt = 0; kt < 2; ++kt)
#pragma unroll
    for (int d = 0; d < 2; ++d){
      float v0 = st[kt*8+4*d+0]*mtv[kt*8+4*d+0];
      float v1 = st[kt*8+4*d+1]*mtv[kt*8+4*d+1];
      float v2 = st[kt*8+4*d+2]*mtv[kt*8+4*d+2];
      float v3 = st[kt*8+4*d+3]*mtv[kt*8+4*d+3];
      int w = cvtpk_fp8<false>(v0, v1, 0);
      xbi[kt][d] = cvtpk_fp8<true>(v2, v3, w);
    }
  const int kti = i>>4, di = (i>>2)&1, sh = 8*(i&3);
  const int msk = ~(0xFF << sh);
  int pz = cvtpk_fp8<false>(zvv, 0.f, 0) & 0xFF;
  int ins = pz << sh;
#pragma unroll
  for (int kt = 0; kt < 2; ++kt)
#pragma unroll
    for (int d = 0; d < 2; ++d)
      if (kt == kti && d == di){
        int mod = (xbi[kt][d] & msk) | ins;
        xbi[kt][d] = hm ? mod : xbi[kt][d];
      }
#pragma unroll
  for (int kt = 0; kt < 2; ++kt)
    xb[kt] = (long)(((unsigned long)(unsigned)xbi[kt][0]) |
                    ((unsigned long)(unsigned)xbi[kt][1] << 32));
}

static __device__ __forceinline__ i32x8 ld_mx(const unsigned char* __restrict__ p){
  union { int4 h[2]; i32x8 v; } u;
  u.h[0] = *(const int4*)(p);
  u.h[1] = *(const int4*)(p + 16);
  return u.v;
}

static __device__ __forceinline__ i32x8 ld_mx_lds(const int4* base, int f, int lane){
  union { int4 h[2]; i32x8 v; } u;
  u.h[0] = base[(f*2+0)*64 + lane];
  u.h[1] = base[(f*2+1)*64 + lane];
  return u.v;
}

// ---- main kernel: 512 blocks x 256 threads = 2048 waves = 2 waves/SIMD ----
// One 32-row tile/wave; W1/W2 + bias frags in LDS; per-step Wi frags double-buffered
// in LDS via global_load_lds. ALL biases enter via K-slice MFMAs (zero VALU).
__global__ __launch_bounds__(256) __attribute__((amdgpu_waves_per_eu(2, 2)))
void genkern(const float* __restrict__ x, const float* __restrict__ z,
             const float* __restrict__ bf,
             const unsigned char* __restrict__ wip, const unsigned char* __restrict__ w1p,
             const unsigned char* __restrict__ w2p, const unsigned char* __restrict__ wfp,
             const unsigned char* __restrict__ bbp, const float* __restrict__ Mt,
             float* __restrict__ out)
{
  __shared__ int4 wlds[2048];          // 32 KB: W1 frags 0-7, W2 frags 8-15 (MX)
  __shared__ long wbias[512];          // 4 KB: K=16 bias frags (b1 x4, b2 x4)
  __shared__ long wibuf[2][768];       // 2 x 6 KB: per-step Wi frags (12 x 64 longs)

  const int tid  = (int)threadIdx.x;
  const int lane = tid & 63;
  const int wv   = tid >> 6;
  const int half = lane >> 5, col = lane & 31;
  const long rbase = (long)blockIdx.x * 128 + wv * 32;

#define STAGE_WIP(stepv, parv) do {                                              \
    const unsigned char* _s = wip + (size_t)(stepv)*6144;                        \
    {                                                                            \
      __builtin_amdgcn_global_load_lds(                                          \
        (const __attribute__((address_space(1))) void*)(_s + wv*1024 + lane*16), \
        (__attribute__((address_space(3))) void*)((char*)&wibuf[parv][0] + wv*1024), \
        16, 0, 0);                                                               \
    }                                                                            \
    if (wv < 2){                                                                 \
      __builtin_amdgcn_global_load_lds(                                          \
        (const __attribute__((address_space(1))) void*)(_s + (4+wv)*1024 + lane*16), \
        (__attribute__((address_space(3))) void*)((char*)&wibuf[parv][0] + (4+wv)*1024), \
        16, 0, 0);                                                               \
    }                                                                            \
  } while(0)

  // weights + bias frags to LDS + stage step 0
  {
    const int4* s1 = (const int4*)w1p;
    const int4* s2 = (const int4*)w2p;
#pragma unroll
    for (int t = 0; t < 4; ++t)
      wlds[t*256 + tid] = s1[t*256 + tid];
#pragma unroll
    for (int t = 0; t < 4; ++t)
      wlds[1024 + t*256 + tid] = s2[t*256 + tid];
#pragma unroll
    for (int t = 0; t < 2; ++t)
      wbias[t*256 + tid] = ((const long*)bbp)[t*256 + tid];
  }
  STAGE_WIP(0, 0);

  // out-state: lane(half h) holds k = kt*16 + h*8 + j at slot kt*8+j
  float st[16];
#pragma unroll
  for (int kt = 0; kt < 2; ++kt)
    ld8(x + (rbase + col)*XD + kt*16 + half*8, &st[kt*8]);

  __syncthreads();   // weights + step-0 staging complete (implicit vmcnt drain)

  f32x16 zro;
#pragma unroll
  for (int q = 0; q < 16; ++q) zro[q] = 0.f;

  const long bconst = (half == 0) ? 0x38L : 0L;   // e4m3 1.0 at k_local=0

  i32x8 wfx[2];
  wfx[0] = ld_mx(wfp + ((size_t)0*64 + lane)*32);
  wfx[1] = ld_mx(wfp + ((size_t)1*64 + lane)*32);
  float zA = z[(rbase + col)*XD + 0];

#pragma unroll 1
  for (int i = 0; i < XD; ++i){
    const int ip = (i + 1) & (XD - 1);
    const int c = i & 1;
    const bool hm = (half == ((i>>3)&1));
    const int slot_i = ((i>>4)<<3) | (i&7);
    const float bfv = bf[i];

    // stage next step's Wi frags into the other buffer (overlaps compute)
    STAGE_WIP(ip, c ^ 1);

    float mtv[16];
#pragma unroll
    for (int kt = 0; kt < 2; ++kt)
      ld8(Mt + i*32 + kt*16 + half*8, &mtv[kt*8]);

    long xb[2];
    pack_xb(st, mtv, zA, i, hm, xb);
    zA = z[(rbase + col)*XD + ip];

    // ---- input layer: K=48 via 3x K=16 fp8 MFMA (kt=2 is bias slice), C=zro ----
    f32x16 acc[4];
#pragma unroll
    for (int fo = 0; fo < 4; ++fo){
      long a = wibuf[c][(0*4+fo)*64 + lane];
      acc[fo] = __builtin_amdgcn_mfma_f32_32x32x16_fp8_fp8(a, xb[0], zro, 0,0,0);
    }
#pragma unroll
    for (int fo = 0; fo < 4; ++fo){
      long a = wibuf[c][(1*4+fo)*64 + lane];
      acc[fo] = __builtin_amdgcn_mfma_f32_32x32x16_fp8_fp8(a, xb[1], acc[fo], 0,0,0);
    }
#pragma unroll
    for (int fo = 0; fo < 4; ++fo){
      long a = wibuf[c][(2*4+fo)*64 + lane];
      acc[fo] = __builtin_amdgcn_mfma_f32_32x32x16_fp8_fp8(a, bconst, acc[fo], 0,0,0);
    }

    // ---- layer 1: bias K-slice MFMA + 2 MX per fo (all operands from LDS) ----
    {
      i32x8 mx0 = c2mx(acc[0], acc[1]);
      i32x8 mx1 = c2mx(acc[2], acc[3]);
#pragma unroll
      for (int fo = 0; fo < 4; ++fo){
        long bfr = wbias[fo*64 + lane];
        acc[fo] = __builtin_amdgcn_mfma_f32_32x32x16_fp8_fp8(bfr, bconst, zro, 0,0,0);
      }
#pragma unroll
      for (int fo = 0; fo < 4; ++fo){
        i32x8 w = ld_mx_lds(wlds, fo*2+0, lane);
        acc[fo] = mfma_mx(w, mx0, acc[fo]);
      }
#pragma unroll
      for (int fo = 0; fo < 4; ++fo){
        i32x8 w = ld_mx_lds(wlds, fo*2+1, lane);
        acc[fo] = mfma_mx(w, mx1, acc[fo]);
      }
    }

    // ---- layer 2: bias K-slice MFMA + 2 MX per fo ----
    {
      i32x8 mx0 = c2mx(acc[0], acc[1]);
      i32x8 mx1 = c2mx(acc[2], acc[3]);
#pragma unroll
      for (int fo = 0; fo < 4; ++fo){
        long bfr = wbias[(4+fo)*64 + lane];
        acc[fo] = __builtin_amdgcn_mfma_f32_32x32x16_fp8_fp8(bfr, bconst, zro, 0,0,0);
      }
#pragma unroll
      for (int fo = 0; fo < 4; ++fo){
        i32x8 w = ld_mx_lds(wlds, 8 + fo*2+0, lane);
        acc[fo] = mfma_mx(w, mx0, acc[fo]);
      }
#pragma unroll
      for (int fo = 0; fo < 4; ++fo){
        i32x8 w = ld_mx_lds(wlds, 8 + fo*2+1, lane);
        acc[fo] = mfma_mx(w, mx1, acc[fo]);
      }
    }

    // ---- epilogue: u = (64wf).fp8(relu(512 h3)) via 2-chain MX, C=zro ----
    {
      i32x8 mx0 = c2mx(acc[0], acc[1]);
      i32x8 mx1 = c2mx(acc[2], acc[3]);
      f32x16 e = mfma_mx(wfx[0], mx0, zro);
      e = mfma_mx(wfx[1], mx1, e);
      float u = e[0];
      float s = __shfl_xor(u, 32, 64);
      float t = half ? s : u;
      float v = 1.f/(1.f + __expf(-(t*(1.f/32768.f) + bfv)));
#pragma unroll
      for (int q = 0; q < 16; ++q)
        if (q == slot_i)
          st[q] = hm ? v : st[q];
    }
    // prefetch next step's wf frags (global, L2-hot)
    wfx[0] = ld_mx(wfp + ((size_t)(ip*2 + 0)*64 + lane)*32);
    wfx[1] = ld_mx(wfp + ((size_t)(ip*2 + 1)*64 + lane)*32);

    __syncthreads();   // staged writes visible + all reads of wibuf[c] done
  }

  // write out
#pragma unroll
  for (int kt = 0; kt < 2; ++kt){
    float* p = out + (rbase + col)*XD + kt*16 + half*8;
    float4 a, b;
    a.x = st[kt*8+0]; a.y = st[kt*8+1]; a.z = st[kt*8+2]; a.w = st[kt*8+3];
    b.x = st[kt*8+4]; b.y = st[kt*8+5]; b.z = st[kt*8+6]; b.w = st[kt*8+7];
    *(float4*)p = a;
    *(float4*)(p+4) = b;
  }
#undef STAGE_WIP
}

extern "C" void kernel_launch(void* const* d_in, const int* in_sizes, int n_in,
                              void* d_out, int out_size, void* d_ws, size_t ws_size,
                              hipStream_t stream){
  (void)in_sizes; (void)n_in; (void)out_size; (void)ws_size;
  const float* x  = (const float*)d_in[0];
  const float* z  = (const float*)d_in[1];
  const float* M  = (const float*)d_in[2];
  const float* Wi = (const float*)d_in[3];
  const float* bi = (const float*)d_in[4];
  const float* wf = (const float*)d_in[5];
  const float* bf = (const float*)d_in[6];
  const float* W1 = (const float*)d_in[7];
  const float* b1 = (const float*)d_in[8];
  const float* W2 = (const float*)d_in[9];
  const float* b2 = (const float*)d_in[10];

  unsigned char* wip = (unsigned char*)d_ws;            // 384*512 = 196608
  unsigned char* w1p = wip + 196608;                    // 16384
  unsigned char* w2p = w1p + 16384;                     // 16384
  unsigned char* wfp = w2p + 16384;                     // 131072
  unsigned char* bbp = wfp + 131072;                    // 4096
  float*         Mt  = (float*)(bbp + 4096);            // 4096

  prep<<<dim3(466), dim3(64), 0, stream>>>(Wi, bi, W1, b1, W2, b2, M, wf,
                                           wip, w1p, w2p, wfp, bbp, Mt);
  genkern<<<dim3(512), dim3(256), 0, stream>>>(x, z, bf, wip, w1p, w2p, wfp, bbp,
                                               Mt, (float*)d_out);
}